// Round 13
// baseline (478.649 us; speedup 1.0000x reference)
//
#include <hip/hip_runtime.h>
#include <math.h>

#define Bsz 16
#define Cch 256
#define Lsq 2048
#define Emb 512
#define Nst 64
#define Hch 512   // 2C
#define KGP 2240  // padded reversed-kernel pitch per h

typedef _Float16 f16;
typedef _Float16 f16x8 __attribute__((ext_vector_type(8)));
typedef _Float16 f16x4 __attribute__((ext_vector_type(4)));
typedef _Float16 f16x2 __attribute__((ext_vector_type(2)));
typedef float f32x4 __attribute__((ext_vector_type(4)));
typedef uint32_t u32x4 __attribute__((ext_vector_type(4)));

__device__ __forceinline__ float sigmoidf_(float x) { return 1.0f/(1.0f + __expf(-x)); }
// gelu_tanh(y) = 0.5*y*(1+tanh(z)) = y - y/(exp(2z)+1), z = 0.7979*(y+0.044715*y^3)
__device__ __forceinline__ float gelu_tanh(float y) {
  float z = 0.7978845608028654f*(y + 0.044715f*y*y*y);
  float zc = fminf(fmaxf(z, -12.f), 12.f);
  float e = __expf(2.f*zc);
  return y - y/(e + 1.f);
}
__device__ __forceinline__ float tanh_fast(float x) {
  float xc = fminf(fmaxf(x, -15.f), 15.f);
  float e = __expf(2.f*xc);
  return (e - 1.f)/(e + 1.f);
}

// async global->LDS, 16B per lane; lds base must be wave-uniform (HW: base + lane*16)
__device__ __forceinline__ void gload_lds16(const f16* g, f16* l) {
  __builtin_amdgcn_global_load_lds(
      (const __attribute__((address_space(1))) void*)g,
      (__attribute__((address_space(3))) void*)l, 16, 0, 0);
}

// ---------------- merged prep kernel ----------------
// blocks [0,1024):    d[b][c] = emb[b].dpW[c] + dpb[c]  (one wave per (b,c))
// blocks [1024,2304): f32->f16 of 4 weight tensors (float4 vectorized)
// blocks [2304,3328): kernel generation, s4prep folded in (both layers)
__global__ __launch_bounds__(256) void k_prep(
    const float* __restrict__ emb, const float* __restrict__ dpW,
    const float* __restrict__ dpb, float* __restrict__ d,
    const float* __restrict__ w1s, f16* __restrict__ w1d,
    const float* __restrict__ w2s, f16* __restrict__ w2d,
    const float* __restrict__ w3s, f16* __restrict__ w3d,
    const float* __restrict__ w4s, f16* __restrict__ w4d,
    const float* __restrict__ ld0, const float* __restrict__ Ar0, const float* __restrict__ Ai0,
    const float* __restrict__ Cr0, const float* __restrict__ Ci0, const float* __restrict__ D0,
    const float* __restrict__ ld1, const float* __restrict__ Ar1, const float* __restrict__ Ai1,
    const float* __restrict__ Cr1, const float* __restrict__ Ci1, const float* __restrict__ D1,
    f16* __restrict__ Ke0, f16* __restrict__ Ko0,
    f16* __restrict__ Ke1, f16* __restrict__ Ko1) {
  int bid = blockIdx.x, tid = threadIdx.x;
  if (bid < 1024) {
    // ---- emb matvec ----
    int wid = bid*4 + (tid >> 6);
    int lane = tid & 63;
    int b = wid >> 8, c = wid & 255;
    const float4* e4 = (const float4*)(emb + (size_t)b*Emb);
    const float4* w4 = (const float4*)(dpW + (size_t)c*Emb);
    float4 ev0 = e4[lane*2], ev1 = e4[lane*2 + 1];
    float4 wv0 = w4[lane*2], wv1 = w4[lane*2 + 1];
    float s = ev0.x*wv0.x + ev0.y*wv0.y + ev0.z*wv0.z + ev0.w*wv0.w
            + ev1.x*wv1.x + ev1.y*wv1.y + ev1.z*wv1.z + ev1.w*wv1.w;
    #pragma unroll
    for (int off = 32; off; off >>= 1) s += __shfl_xor(s, off);
    if (lane == 0) d[b*Cch + c] = dpb[c] + s;
    return;
  }
  if (bid < 2304) {
    // ---- f2h of 4 weight tensors ----
    int i = (bid - 1024)*256 + tid;
    const float* s; f16* dd; int off;
    if (i < 32768)        { s = w1s; dd = w1d; off = 0; }
    else if (i < 163840)  { s = w2s; dd = w2d; off = 32768; }
    else if (i < 294912)  { s = w3s; dd = w3d; off = 163840; }
    else                  { s = w4s; dd = w4d; off = 294912; }
    int j = i - off;
    float4 v = ((const float4*)s)[j];
    f16x4 o;
    o[0] = (f16)v.x; o[1] = (f16)v.y; o[2] = (f16)v.z; o[3] = (f16)v.w;
    ((f16x4*)dd)[j] = o;
    return;
  }
  // ---- kgen (s4prep folded) ----
  __shared__ float2 wbt[64][65];   // [n][j]
  __shared__ float2 wat[32][66];   // [a][n]
  __shared__ float2 ccs[64];
  __shared__ float Kf[2048];
  int h2 = bid - 2304;
  int ly = h2 >> 9, h = h2 & 511;
  const float* log_dt = ly ? ld1 : ld0;
  const float* A_re = ly ? Ar1 : Ar0;
  const float* A_im = ly ? Ai1 : Ai0;
  const float* C_re = ly ? Cr1 : Cr0;
  const float* C_im = ly ? Ci1 : Ci0;
  const float* Dvec = ly ? D1 : D0;
  f16* Ke = ly ? Ke1 : Ke0;
  f16* Ko = ly ? Ko1 : Ko0;
  if (tid < 64) {
    int n = tid;
    int i = h*64 + n;
    float dt = expf(log_dt[h]);
    float Arv = A_re[i], Aiv = A_im[i];
    float er = expf(dt*Arv);
    float wrf = er*cosf(dt*Aiv), wif = er*sinf(dt*Aiv);
    float mag = Arv*Arv + Aiv*Aiv;
    float nr = wrf - 1.0f, ni = wif;
    float qr = (nr*Arv + ni*Aiv)/mag, qi = (ni*Arv - nr*Aiv)/mag;
    float cr = C_re[i], ci = C_im[i];
    float trc = cr*qr - ci*qi, tic = cr*qi + ci*qr;
    double wr = (double)wrf, wi = (double)wif;
    double br = 1.0, bi = 0.0;
    for (int j = 0; j < 64; ++j) {
      wbt[n][j] = make_float2((float)br, (float)bi);
      double t = br*wr - bi*wi; bi = br*wi + bi*wr; br = t;
    }
    double ar = 1.0, ai = 0.0;   // (br,bi) = w^64 now
    for (int a = 0; a < 32; ++a) {
      wat[a][n] = make_float2((float)ar, (float)ai);
      double t = ar*br - ai*bi; ai = ar*bi + ai*br; ar = t;
    }
    ccs[n] = make_float2(2.0f*trc, -2.0f*tic);
  }
  __syncthreads();
  int lane = tid & 63, wv = tid >> 6;
  float acc[8] = {0.f,0.f,0.f,0.f,0.f,0.f,0.f,0.f};
  for (int n = 0; n < 64; ++n) {
    float2 wb = wbt[n][lane];
    float2 cc = ccs[n];
    float tr = fmaf(cc.y, wb.y,  cc.x*wb.x);
    float ti = fmaf(cc.y, wb.x, -cc.x*wb.y);
    #pragma unroll
    for (int li = 0; li < 8; ++li) {
      float2 wa = wat[wv + 4*li][n];
      acc[li] = fmaf(wa.x, tr, acc[li]);
      acc[li] = fmaf(wa.y, ti, acc[li]);
    }
  }
  #pragma unroll
  for (int li = 0; li < 8; ++li)
    Kf[(wv + 4*li)*64 + lane] = acc[li];
  __syncthreads();
  if (tid == 0) Kf[0] += Dvec[h];
  __syncthreads();
  f16* keh = Ke + (size_t)h*KGP;
  f16* koh = Ko + (size_t)h*KGP;
  for (int q = tid; q < KGP; q += 256) {
    float e = (q < 2048) ? Kf[2047 - q] : 0.f;   // KR[q] = K[2047-q]
    float o = (q < 2047) ? Kf[2046 - q] : 0.f;   // KRo[q] = KR[q+1]
    keh[q] = (f16)e; koh[q] = (f16)o;
  }
}

// ---------------- S4 causal conv as Toeplitz MFMA + GELU ----------------
// (R9 proven version: W[8] ring, parity-hoisted kernel base, 8 waves, balanced panels)
__device__ __forceinline__ f16x8 ld4u32(const uint32_t* __restrict__ p) {
  union { uint32_t u[4]; f16x8 v; } r;
  r.u[0] = p[0]; r.u[1] = p[1]; r.u[2] = p[2]; r.u[3] = p[3];
  return r.v;
}

__global__ __launch_bounds__(512) void k_conv(
    const f16* __restrict__ u, const f16* __restrict__ Ke, const f16* __restrict__ Ko,
    f16* __restrict__ g) {
  __shared__ __align__(16) f16 Ul[16*2048];   // exactly 64 KB
  int h = blockIdx.x, tid = threadIdx.x;
  {
    int b = tid >> 5, pr = tid & 31;          // 16 batches x 32 threads
    const f16* src = u + ((size_t)b*Hch + h)*Lsq;
    f16* dst = &Ul[b*2048];
    #pragma unroll
    for (int c = 0; c < 8; ++c) {
      int gs = c*32 + pr;                     // granule (8 f16)
      *(f16x8*)&dst[(gs ^ b)*8] = *(const f16x8*)(src + gs*8);
    }
  }
  __syncthreads();
  int wv = tid >> 6, lane = tid & 63;
  int m = lane & 15, qd = lane >> 4;
  const f16* keh = Ke + (size_t)h*KGP;
  const f16* koh = Ko + (size_t)h*KGP;
  // q parity = parity(2047-m): m odd -> q even -> ke ; m even -> q odd -> ko
  const uint32_t* kb = (m & 1) ? (const uint32_t*)keh : (const uint32_t*)koh;
  f16* gb = g + ((size_t)m*Hch + h)*Lsq;      // output batch = m
  const f16* ulb = &Ul[m*2048];
  for (int pi = 0; pi < 2; ++pi) {
    int P = pi ? (15 - wv) : wv;
    int i0 = P*128;
    int qb0 = 2047 - i0 - m + qd*8;
    int ib = qb0 >> 1;                        // dword index; all deltas even
    f32x4 acc[8];
    #pragma unroll
    for (int t = 0; t < 8; ++t) acc[t] = (f32x4){0.f,0.f,0.f,0.f};
    f16x8 W[8];
    #pragma unroll
    for (int t = 0; t < 8; ++t) W[t] = ld4u32(kb + ib - 8*t);
    int steps = 4*(P+1);
    for (int s4i = 0; s4i < steps; s4i += 4) {
      const uint32_t* pw = kb + ib + 16*(s4i + 1);
      #pragma unroll
      for (int ph = 0; ph < 4; ++ph) {
        int s = s4i + ph;
        f16x8 bf = *(const f16x8*)&ulb[((4*s + qd) ^ m)*8];
        f16x8 nf0 = ld4u32(pw + 16*ph);       // q = qb0 + 32*(s+1)
        f16x8 nf1 = ld4u32(pw + 16*ph - 8);   // q = qb0 - 16 + 32*(s+1)
        __builtin_amdgcn_s_setprio(1);
        #pragma unroll
        for (int t = 0; t < 8; ++t)
          acc[t] = __builtin_amdgcn_mfma_f32_16x16x32_f16(W[(t - 2*ph) & 7], bf, acc[t], 0, 0, 0);
        __builtin_amdgcn_s_setprio(0);
        W[(6 - 2*ph) & 7] = nf0;
        W[(7 - 2*ph) & 7] = nf1;
      }
    }
    #pragma unroll
    for (int t = 0; t < 8; ++t) {
      f16x4 o;
      #pragma unroll
      for (int r = 0; r < 4; ++r) o[r] = (f16)gelu_tanh(acc[t][r]);
      *(f16x4*)&gb[i0 + 16*t + qd*4] = o;
    }
  }
}

// ------ MFMA fp16 GEMM, 8 waves (2m x 4n), BM=256 (2 paired 128-row tiles), BN=256 ----
// EXACT R6/R9 structure (measured fastest: MODE1 61.5 us, 59 MB traffic).
// MODE 0 additionally FUSES the diffusion-embedding add: B is read as f32 from x and
// d[b][c] is added during the register pair-pack (replaces the k_addemb pass).
// A: global_load_lds w16, As[row][8 slots] 128B pitch, slot=(tile*4+kg)^(row&7).
// B: coalesced row loads + register pair-pack into Bs[kp][n], pitch 260 words.
// Grid: 1D + bijective XCD swizzle (consecutive lin share nt -> B-tile L2 locality).
// MODE 0: out fp16 rows mg, mg+256 = W@(x+d) + bias  (in-projection, M=512)
// MODE 1: out fp16 = (gate row mg)*sigmoid(filter row mg+512)  (oW+GLU, M=1024->512)
// MODE 2: out fp32: tile0 -> (x+v)/sqrt2 (residual), tile1 (+256) -> skip  (M=512)
template<int KD, int MODE>
__global__ __launch_bounds__(512) void k_gemm(
    const f16* __restrict__ W, const f16* __restrict__ Bact,
    const float* __restrict__ bias, const float* __restrict__ xres,
    float* __restrict__ outF, f16* __restrict__ outH,
    const float* __restrict__ Bf32, const float* __restrict__ dadd) {
  constexpr int TOFF = (MODE == 1) ? 512 : 256;   // row offset of second A tile
  constexpr int NK = KD/32;
  constexpr int MT = (MODE == 1) ? 4 : 2;         // m-tiles
  __shared__ __align__(16) f16 As[2][128*8*8];    // [buf][row*8+slot][8], 16 KB/buf
  __shared__ __align__(16) uint32_t Bs[2][16*260];// [buf][kp][n], 16.6 KB/buf
  int tid = threadIdx.x;
  int wv = tid >> 6, lane = tid & 63;

  // bijective XCD swizzle (nwg = 128*MT, divisible by 8)
  int nwg = 128*MT;
  int bid = blockIdx.x;
  int lin = (bid & 7)*(nwg >> 3) + (bid >> 3);
  int mt = lin % MT;
  int nt = lin / MT;              // consecutive lin share nt -> B-tile
  int bb = nt >> 3;
  int l0 = (nt & 7)*256;
  int m0 = mt*128;
  int wm = (wv & 1)*64, wn = (wv >> 1)*64;
  int qd = lane >> 4, ln16 = lane & 15;

  f32x4 acc[2][4][4];
  #pragma unroll
  for (int t = 0; t < 2; ++t)
    for (int i = 0; i < 4; ++i)
      for (int j = 0; j < 4; ++j)
        acc[t][i][j] = (f32x4){0.f,0.f,0.f,0.f};

  const f16* Bbase = Bact + (size_t)bb*KD*Lsq + l0;
  const float* Bfb = Bf32 + (size_t)bb*KD*Lsq + l0;
  int q16 = tid >> 5, nch = tid & 31;

  // ---- pipeline helpers ----
  auto stageA = [&](int buf, int kk) {
    #pragma unroll
    for (int i = 0; i < 2; ++i) {
      int gbase = (wv*2 + i)*64;                 // wave-uniform granule base
      int G = gbase + lane;                      // granule id 0..1023
      int row = G >> 3;
      int gsw = (G & 7) ^ (row & 7);             // source granule (tile*4 + kgran)
      int t = gsw >> 2;
      const f16* src = W + (size_t)(m0 + row + t*TOFF)*KD + kk + (gsw & 3)*8;
      gload_lds16(src, &As[buf][gbase*8]);
    }
  };
  f16x8 rb0, rb1;                 // MODE 1/2 staging regs
  float4 r0l, r0h, r1l, r1h;      // MODE 0 staging regs (f32)
  float d0, d1;
  auto loadB = [&](int kk) {
    if constexpr (MODE == 0) {
      const float* b0 = Bfb + (size_t)(kk + 2*q16)*Lsq + nch*8;
      r0l = *(const float4*)b0;      r0h = *(const float4*)(b0 + 4);
      r1l = *(const float4*)(b0 + Lsq); r1h = *(const float4*)(b0 + Lsq + 4);
      d0 = dadd[bb*Cch + kk + 2*q16];
      d1 = dadd[bb*Cch + kk + 2*q16 + 1];
    } else {
      const f16* b0 = Bbase + (size_t)(kk + 2*q16)*Lsq + nch*8;
      rb0 = *(const f16x8*)b0;
      rb1 = *(const f16x8*)(b0 + Lsq);
    }
  };
  auto packB = [&](int buf) {
    union { uint32_t w[8]; u32x4 v[2]; } pk;
    if constexpr (MODE == 0) {
      float a0[8] = {r0l.x,r0l.y,r0l.z,r0l.w,r0h.x,r0h.y,r0h.z,r0h.w};
      float a1[8] = {r1l.x,r1l.y,r1l.z,r1l.w,r1h.x,r1h.y,r1h.z,r1h.w};
      #pragma unroll
      for (int e = 0; e < 8; ++e) {
        union { f16 h2[2]; uint32_t u; } t2;
        t2.h2[0] = (f16)(a0[e] + d0); t2.h2[1] = (f16)(a1[e] + d1);
        pk.w[e] = t2.u;
      }
    } else {
      #pragma unroll
      for (int e = 0; e < 8; ++e) {
        union { f16 h2[2]; uint32_t u; } t2;
        t2.h2[0] = rb0[e]; t2.h2[1] = rb1[e];
        pk.w[e] = t2.u;
      }
    }
    *(u32x4*)&Bs[buf][q16*260 + nch*8]     = pk.v[0];
    *(u32x4*)&Bs[buf][q16*260 + nch*8 + 4] = pk.v[1];
  };
  auto compute = [&](int buf) {
    f16x8 afr[2][4];
    #pragma unroll
    for (int i = 0; i < 4; ++i)
      for (int t = 0; t < 2; ++t) {
        int row = wm + i*16 + ln16;
        int g = (t*4 + qd) ^ (row & 7);          // undo source swizzle
        afr[t][i] = *(const f16x8*)&As[buf][(row*8 + g)*8];
      }
    f16x8 bfr[4];
    #pragma unroll
    for (int j = 0; j < 4; ++j) {
      union { uint32_t w2[4]; f16x8 v; } bu;
      #pragma unroll
      for (int r2 = 0; r2 < 4; ++r2) bu.w2[r2] = Bs[buf][(qd*4 + r2)*260 + wn + j*16 + ln16];
      bfr[j] = bu.v;
    }
    __builtin_amdgcn_s_setprio(1);
    #pragma unroll
    for (int j = 0; j < 4; ++j)
      for (int i = 0; i < 4; ++i)
        for (int t = 0; t < 2; ++t)
          acc[t][i][j] = __builtin_amdgcn_mfma_f32_16x16x32_f16(afr[t][i], bfr[j], acc[t][i][j], 0, 0, 0);
    __builtin_amdgcn_s_setprio(0);
  };

  // ---- prologue: fill buffer 0 ----
  stageA(0, 0);
  loadB(0);
  packB(0);
  __syncthreads();

  int cur = 0;
  for (int t = 0; t < NK; ++t) {
    if (t + 1 < NK) {                            // issue next-tile loads EARLY
      stageA(cur ^ 1, (t + 1)*32);
      loadB((t + 1)*32);
    }
    compute(cur);                                // hides the load latency
    if (t + 1 < NK) packB(cur ^ 1);              // write-late (rb done by now)
    __syncthreads();                             // single drain+publish per K-step
    cur ^= 1;
  }

  #pragma unroll
  for (int i = 0; i < 4; ++i)
    for (int j = 0; j < 4; ++j)
      for (int r = 0; r < 4; ++r) {
        int ml = wm + i*16 + qd*4 + r;
        int nl = wn + j*16 + ln16;
        int mg = m0 + ml;
        int l  = l0 + nl;
        if (MODE == 0) {
          outH[((size_t)bb*Hch + mg)*Lsq + l]       = (f16)(acc[0][i][j][r] + bias[mg]);
          outH[((size_t)bb*Hch + mg + 256)*Lsq + l] = (f16)(acc[1][i][j][r] + bias[mg + 256]);
        } else if (MODE == 1) {
          float va = acc[0][i][j][r] + bias[mg];
          float vb = acc[1][i][j][r] + bias[512 + mg];
          outH[((size_t)bb*Hch + mg)*Lsq + l] = (f16)(va * sigmoidf_(vb));
        } else {
          size_t idx = ((size_t)bb*Cch + mg)*Lsq + l;
          float v0 = acc[0][i][j][r] + bias[mg];
          outF[idx] = (v0 + xres[idx]) * 0.7071067811865476f;
          float v1 = acc[1][i][j][r] + bias[mg + 256];
          outF[(size_t)Bsz*Cch*Lsq + idx] = v1;
        }
      }
}

// ---------------- fused LayerNorm over channels (fp16 in), 2 columns/lane ----------------
// Block covers 128 l's (f16x2 per lane -> 256B/wave/row, full coalescing). Grid Bsz*16.
// Per-column reduction order identical to the 1-col version (same h partition per wave).
template<int MODE>
__global__ __launch_bounds__(256) void k_ln(const f16* __restrict__ v,
                                            const float* __restrict__ gam, const float* __restrict__ bet,
                                            float* __restrict__ outF, f16* __restrict__ outH) {
  __shared__ float red[2][4][128];
  __shared__ float muL[128], rsL[128];
  int tid = threadIdx.x;
  int b = blockIdx.x >> 4;
  int l0 = (blockIdx.x & 15)*128;
  int wv = tid >> 6, lane = tid & 63;
  const f16* base = v + (size_t)b*Hch*Lsq + l0 + lane*2;
  float s0 = 0.f, s1 = 0.f, q0 = 0.f, q1 = 0.f;
  for (int h = wv*128; h < wv*128 + 128; ++h) {
    f16x2 xv = *(const f16x2*)(base + (size_t)h*Lsq);
    float a = (float)xv[0], c = (float)xv[1];
    s0 += a; q0 += a*a; s1 += c; q1 += c*c;
  }
  red[0][wv][lane*2] = s0; red[0][wv][lane*2+1] = s1;
  red[1][wv][lane*2] = q0; red[1][wv][lane*2+1] = q1;
  __syncthreads();
  if (tid < 128) {
    float ss = red[0][0][tid] + red[0][1][tid] + red[0][2][tid] + red[0][3][tid];
    float s2 = red[1][0][tid] + red[1][1][tid] + red[1][2][tid] + red[1][3][tid];
    float mu = ss*(1.0f/Hch);
    float var = s2*(1.0f/Hch) - mu*mu;
    muL[tid] = mu; rsL[tid] = rsqrtf(var + 1e-5f);
  }
  __syncthreads();
  float mu0 = muL[lane*2], mu1 = muL[lane*2+1];
  float rs0 = rsL[lane*2], rs1 = rsL[lane*2+1];
  if (MODE == 0) {
    f16* ob = outH + (size_t)b*Hch*Lsq + l0 + lane*2;
    for (int h = wv*128; h < wv*128 + 128; ++h) {
      f16x2 xv = *(const f16x2*)(base + (size_t)h*Lsq);
      float g = gam[h], be = bet[h];
      f16x2 o;
      o[0] = (f16)(((float)xv[0] - mu0)*rs0*g + be);
      o[1] = (f16)(((float)xv[1] - mu1)*rs1*g + be);
      *(f16x2*)(ob + (size_t)h*Lsq) = o;
    }
  } else {
    f16* ob = outH + (size_t)b*Cch*Lsq + l0 + lane*2;
    for (int c = wv*64; c < wv*64 + 64; ++c) {
      f16x2 xg2 = *(const f16x2*)(base + (size_t)c*Lsq);
      f16x2 xf2 = *(const f16x2*)(base + (size_t)(c + Cch)*Lsq);
      float g1 = gam[c], b1 = bet[c], g2 = gam[c + Cch], b2 = bet[c + Cch];
      f16x2 o;
      {
        float xg = ((float)xg2[0] - mu0)*rs0*g1 + b1;
        float xf = ((float)xf2[0] - mu0)*rs0*g2 + b2;
        o[0] = (f16)(sigmoidf_(xg) * tanh_fast(xf));
      }
      {
        float xg = ((float)xg2[1] - mu1)*rs1*g1 + b1;
        float xf = ((float)xf2[1] - mu1)*rs1*g2 + b2;
        o[1] = (f16)(sigmoidf_(xg) * tanh_fast(xf));
      }
      *(f16x2*)(ob + (size_t)c*Lsq) = o;
    }
  }
}

// ---------------- launch ----------------
extern "C" void kernel_launch(void* const* d_in, const int* in_sizes, int n_in,
                              void* d_out, int out_size, void* d_ws, size_t ws_size,
                              hipStream_t stream) {
  const float* x    = (const float*)d_in[0];
  const float* emb  = (const float*)d_in[1];
  const float* dpW  = (const float*)d_in[2];
  const float* dpb  = (const float*)d_in[3];
  const float* inW  = (const float*)d_in[4];
  const float* inb  = (const float*)d_in[5];
  const float* outW = (const float*)d_in[6];
  const float* outb = (const float*)d_in[7];
  const float* ln1g = (const float*)d_in[8];
  const float* ln1b = (const float*)d_in[9];
  const float* ln2g = (const float*)d_in[10];
  const float* ln2b = (const float*)d_in[11];
  const float* s4[2][8];
  for (int ly = 0; ly < 2; ++ly)
    for (int k = 0; k < 8; ++k) s4[ly][k] = (const float*)d_in[12 + ly*8 + k];
  // s4[ly]: 0 log_dt, 1 A_re, 2 A_im, 3 C_re, 4 C_im, 5 D, 6 oW, 7 ob

  char* p = (char*)d_ws;
  auto alloc = [&](size_t bytes) { char* r = p; p += (bytes + 255) & ~(size_t)255; return r; };
  f16* inW16  = (f16*)alloc((size_t)Hch*Cch*2);
  f16* oW16_0 = (f16*)alloc((size_t)2*Hch*Hch*2);
  f16* oW16_1 = (f16*)alloc((size_t)2*Hch*Hch*2);
  f16* outW16 = (f16*)alloc((size_t)2*Cch*Cch*2);
  float* dbuf = (float*)alloc((size_t)Bsz*Cch*4);
  f16* kge[2], *kgo[2];
  for (int ly = 0; ly < 2; ++ly) {
    kge[ly] = (f16*)alloc((size_t)Hch*KGP*2);
    kgo[ly] = (f16*)alloc((size_t)Hch*KGP*2);
  }
  f16*  xd   = (f16*)alloc((size_t)Bsz*Cch*Lsq*2);
  f16*  u16g = (f16*)alloc((size_t)Bsz*Hch*Lsq*2);
  f16*  gbuf = (f16*)alloc((size_t)Bsz*Hch*Lsq*2);
  f16*  glu  = (f16*)alloc((size_t)Bsz*Hch*Lsq*2);
  f16*  oW16[2] = {oW16_0, oW16_1};

  // prep: ONE launch (emb matvec | weight f2h | kgen both layers)
  k_prep<<<3328, 256, 0, stream>>>(
      emb, dpW, dpb, dbuf,
      inW, inW16, s4[0][6], oW16_0, s4[1][6], oW16_1, outW, outW16,
      s4[0][0], s4[0][1], s4[0][2], s4[0][3], s4[0][4], s4[0][5],
      s4[1][0], s4[1][1], s4[1][2], s4[1][3], s4[1][4], s4[1][5],
      kge[0], kgo[0], kge[1], kgo[1]);

  dim3 bl(512);
  // in-projection (fp16 out), diffusion-emb add fused into B staging
  k_gemm<Cch, 0><<<256, bl, 0, stream>>>(inW16, nullptr, inb, nullptr, nullptr, u16g, x, dbuf);
  // S4 layer 1
  k_conv<<<Hch, 512, 0, stream>>>(u16g, kge[0], kgo[0], gbuf);
  k_gemm<Hch, 1><<<512, bl, 0, stream>>>(oW16[0], gbuf, s4[0][7], nullptr, nullptr, glu, nullptr, nullptr);
  k_ln<0><<<Bsz*16, 256, 0, stream>>>(glu, ln1g, ln1b, nullptr, u16g);
  // S4 layer 2
  k_conv<<<Hch, 512, 0, stream>>>(u16g, kge[1], kgo[1], gbuf);
  k_gemm<Hch, 1><<<512, bl, 0, stream>>>(oW16[1], gbuf, s4[1][7], nullptr, nullptr, glu, nullptr, nullptr);
  k_ln<1><<<Bsz*16, 256, 0, stream>>>(glu, ln2g, ln2b, nullptr, xd);
  // out-projection (+ residual/skip split)
  k_gemm<Cch, 2><<<256, bl, 0, stream>>>(outW16, xd, outb, x, (float*)d_out, nullptr, nullptr, nullptr);
}

// Round 14
// 470.666 us; speedup vs baseline: 1.0170x; 1.0170x over previous
//
#include <hip/hip_runtime.h>
#include <math.h>

#define Bsz 16
#define Cch 256
#define Lsq 2048
#define Emb 512
#define Nst 64
#define Hch 512   // 2C
#define KGP 2240  // padded reversed-kernel pitch per h

typedef _Float16 f16;
typedef _Float16 f16x8 __attribute__((ext_vector_type(8)));
typedef _Float16 f16x4 __attribute__((ext_vector_type(4)));
typedef float f32x4 __attribute__((ext_vector_type(4)));
typedef uint32_t u32x4 __attribute__((ext_vector_type(4)));

__device__ __forceinline__ float sigmoidf_(float x) { return 1.0f/(1.0f + __expf(-x)); }
// gelu_tanh(y) = 0.5*y*(1+tanh(z)) = y - y/(exp(2z)+1), z = 0.7979*(y+0.044715*y^3)
__device__ __forceinline__ float gelu_tanh(float y) {
  float z = 0.7978845608028654f*(y + 0.044715f*y*y*y);
  float zc = fminf(fmaxf(z, -12.f), 12.f);
  float e = __expf(2.f*zc);
  return y - y/(e + 1.f);
}

// async global->LDS, 16B per lane; lds base must be wave-uniform (HW: base + lane*16)
__device__ __forceinline__ void gload_lds16(const f16* g, f16* l) {
  __builtin_amdgcn_global_load_lds(
      (const __attribute__((address_space(1))) void*)g,
      (__attribute__((address_space(3))) void*)l, 16, 0, 0);
}

// ---------------- merged prep kernel ----------------
// blocks [0,1024):    d[b][c] = emb[b].dpW[c] + dpb[c]  (one wave per (b,c))
// blocks [1024,2304): f32->f16 of 4 weight tensors (float4 vectorized)
// blocks [2304,3328): kernel generation, s4prep folded in (both layers)
__global__ __launch_bounds__(256) void k_prep(
    const float* __restrict__ emb, const float* __restrict__ dpW,
    const float* __restrict__ dpb, float* __restrict__ d,
    const float* __restrict__ w1s, f16* __restrict__ w1d,
    const float* __restrict__ w2s, f16* __restrict__ w2d,
    const float* __restrict__ w3s, f16* __restrict__ w3d,
    const float* __restrict__ w4s, f16* __restrict__ w4d,
    const float* __restrict__ ld0, const float* __restrict__ Ar0, const float* __restrict__ Ai0,
    const float* __restrict__ Cr0, const float* __restrict__ Ci0, const float* __restrict__ D0,
    const float* __restrict__ ld1, const float* __restrict__ Ar1, const float* __restrict__ Ai1,
    const float* __restrict__ Cr1, const float* __restrict__ Ci1, const float* __restrict__ D1,
    f16* __restrict__ Ke0, f16* __restrict__ Ko0,
    f16* __restrict__ Ke1, f16* __restrict__ Ko1) {
  int bid = blockIdx.x, tid = threadIdx.x;
  if (bid < 1024) {
    // ---- emb matvec ----
    int wid = bid*4 + (tid >> 6);
    int lane = tid & 63;
    int b = wid >> 8, c = wid & 255;
    const float4* e4 = (const float4*)(emb + (size_t)b*Emb);
    const float4* w4 = (const float4*)(dpW + (size_t)c*Emb);
    float4 ev0 = e4[lane*2], ev1 = e4[lane*2 + 1];
    float4 wv0 = w4[lane*2], wv1 = w4[lane*2 + 1];
    float s = ev0.x*wv0.x + ev0.y*wv0.y + ev0.z*wv0.z + ev0.w*wv0.w
            + ev1.x*wv1.x + ev1.y*wv1.y + ev1.z*wv1.z + ev1.w*wv1.w;
    #pragma unroll
    for (int off = 32; off; off >>= 1) s += __shfl_xor(s, off);
    if (lane == 0) d[b*Cch + c] = dpb[c] + s;
    return;
  }
  if (bid < 2304) {
    // ---- f2h of 4 weight tensors ----
    int i = (bid - 1024)*256 + tid;
    const float* s; f16* dd; int off;
    if (i < 32768)        { s = w1s; dd = w1d; off = 0; }
    else if (i < 163840)  { s = w2s; dd = w2d; off = 32768; }
    else if (i < 294912)  { s = w3s; dd = w3d; off = 163840; }
    else                  { s = w4s; dd = w4d; off = 294912; }
    int j = i - off;
    float4 v = ((const float4*)s)[j];
    f16x4 o;
    o[0] = (f16)v.x; o[1] = (f16)v.y; o[2] = (f16)v.z; o[3] = (f16)v.w;
    ((f16x4*)dd)[j] = o;
    return;
  }
  // ---- kgen (s4prep folded) ----
  __shared__ float2 wbt[64][65];   // [n][j]
  __shared__ float2 wat[32][66];   // [a][n]
  __shared__ float2 ccs[64];
  __shared__ float Kf[2048];
  int h2 = bid - 2304;
  int ly = h2 >> 9, h = h2 & 511;
  const float* log_dt = ly ? ld1 : ld0;
  const float* A_re = ly ? Ar1 : Ar0;
  const float* A_im = ly ? Ai1 : Ai0;
  const float* C_re = ly ? Cr1 : Cr0;
  const float* C_im = ly ? Ci1 : Ci0;
  const float* Dvec = ly ? D1 : D0;
  f16* Ke = ly ? Ke1 : Ke0;
  f16* Ko = ly ? Ko1 : Ko0;
  if (tid < 64) {
    int n = tid;
    int i = h*64 + n;
    float dt = expf(log_dt[h]);
    float Arv = A_re[i], Aiv = A_im[i];
    float er = expf(dt*Arv);
    float wrf = er*cosf(dt*Aiv), wif = er*sinf(dt*Aiv);
    float mag = Arv*Arv + Aiv*Aiv;
    float nr = wrf - 1.0f, ni = wif;
    float qr = (nr*Arv + ni*Aiv)/mag, qi = (ni*Arv - nr*Aiv)/mag;
    float cr = C_re[i], ci = C_im[i];
    float trc = cr*qr - ci*qi, tic = cr*qi + ci*qr;
    double wr = (double)wrf, wi = (double)wif;
    double br = 1.0, bi = 0.0;
    for (int j = 0; j < 64; ++j) {
      wbt[n][j] = make_float2((float)br, (float)bi);
      double t = br*wr - bi*wi; bi = br*wi + bi*wr; br = t;
    }
    double ar = 1.0, ai = 0.0;   // (br,bi) = w^64 now
    for (int a = 0; a < 32; ++a) {
      wat[a][n] = make_float2((float)ar, (float)ai);
      double t = ar*br - ai*bi; ai = ar*bi + ai*br; ar = t;
    }
    ccs[n] = make_float2(2.0f*trc, -2.0f*tic);
  }
  __syncthreads();
  int lane = tid & 63, wv = tid >> 6;
  float acc[8] = {0.f,0.f,0.f,0.f,0.f,0.f,0.f,0.f};
  for (int n = 0; n < 64; ++n) {
    float2 wb = wbt[n][lane];
    float2 cc = ccs[n];
    float tr = fmaf(cc.y, wb.y,  cc.x*wb.x);
    float ti = fmaf(cc.y, wb.x, -cc.x*wb.y);
    #pragma unroll
    for (int li = 0; li < 8; ++li) {
      float2 wa = wat[wv + 4*li][n];
      acc[li] = fmaf(wa.x, tr, acc[li]);
      acc[li] = fmaf(wa.y, ti, acc[li]);
    }
  }
  #pragma unroll
  for (int li = 0; li < 8; ++li)
    Kf[(wv + 4*li)*64 + lane] = acc[li];
  __syncthreads();
  if (tid == 0) Kf[0] += Dvec[h];
  __syncthreads();
  f16* keh = Ke + (size_t)h*KGP;
  f16* koh = Ko + (size_t)h*KGP;
  for (int q = tid; q < KGP; q += 256) {
    float e = (q < 2048) ? Kf[2047 - q] : 0.f;   // KR[q] = K[2047-q]
    float o = (q < 2047) ? Kf[2046 - q] : 0.f;   // KRo[q] = KR[q+1]
    keh[q] = (f16)e; koh[q] = (f16)o;
  }
}

// ---------------- S4 causal conv as Toeplitz MFMA + GELU ----------------
// (R9 proven version: W[8] ring, parity-hoisted kernel base, 8 waves, balanced panels)
__device__ __forceinline__ f16x8 ld4u32(const uint32_t* __restrict__ p) {
  union { uint32_t u[4]; f16x8 v; } r;
  r.u[0] = p[0]; r.u[1] = p[1]; r.u[2] = p[2]; r.u[3] = p[3];
  return r.v;
}

__global__ __launch_bounds__(512) void k_conv(
    const f16* __restrict__ u, const f16* __restrict__ Ke, const f16* __restrict__ Ko,
    f16* __restrict__ g) {
  __shared__ __align__(16) f16 Ul[16*2048];   // exactly 64 KB
  int h = blockIdx.x, tid = threadIdx.x;
  {
    int b = tid >> 5, pr = tid & 31;          // 16 batches x 32 threads
    const f16* src = u + ((size_t)b*Hch + h)*Lsq;
    f16* dst = &Ul[b*2048];
    #pragma unroll
    for (int c = 0; c < 8; ++c) {
      int gs = c*32 + pr;                     // granule (8 f16)
      *(f16x8*)&dst[(gs ^ b)*8] = *(const f16x8*)(src + gs*8);
    }
  }
  __syncthreads();
  int wv = tid >> 6, lane = tid & 63;
  int m = lane & 15, qd = lane >> 4;
  const f16* keh = Ke + (size_t)h*KGP;
  const f16* koh = Ko + (size_t)h*KGP;
  // q parity = parity(2047-m): m odd -> q even -> ke ; m even -> q odd -> ko
  const uint32_t* kb = (m & 1) ? (const uint32_t*)keh : (const uint32_t*)koh;
  f16* gb = g + ((size_t)m*Hch + h)*Lsq;      // output batch = m
  const f16* ulb = &Ul[m*2048];
  for (int pi = 0; pi < 2; ++pi) {
    int P = pi ? (15 - wv) : wv;
    int i0 = P*128;
    int qb0 = 2047 - i0 - m + qd*8;
    int ib = qb0 >> 1;                        // dword index; all deltas even
    f32x4 acc[8];
    #pragma unroll
    for (int t = 0; t < 8; ++t) acc[t] = (f32x4){0.f,0.f,0.f,0.f};
    f16x8 W[8];
    #pragma unroll
    for (int t = 0; t < 8; ++t) W[t] = ld4u32(kb + ib - 8*t);
    int steps = 4*(P+1);
    for (int s4i = 0; s4i < steps; s4i += 4) {
      const uint32_t* pw = kb + ib + 16*(s4i + 1);
      #pragma unroll
      for (int ph = 0; ph < 4; ++ph) {
        int s = s4i + ph;
        f16x8 bf = *(const f16x8*)&ulb[((4*s + qd) ^ m)*8];
        f16x8 nf0 = ld4u32(pw + 16*ph);       // q = qb0 + 32*(s+1)
        f16x8 nf1 = ld4u32(pw + 16*ph - 8);   // q = qb0 - 16 + 32*(s+1)
        __builtin_amdgcn_s_setprio(1);
        #pragma unroll
        for (int t = 0; t < 8; ++t)
          acc[t] = __builtin_amdgcn_mfma_f32_16x16x32_f16(W[(t - 2*ph) & 7], bf, acc[t], 0, 0, 0);
        __builtin_amdgcn_s_setprio(0);
        W[(6 - 2*ph) & 7] = nf0;
        W[(7 - 2*ph) & 7] = nf1;
      }
    }
    #pragma unroll
    for (int t = 0; t < 8; ++t) {
      f16x4 o;
      #pragma unroll
      for (int r = 0; r < 4; ++r) o[r] = (f16)gelu_tanh(acc[t][r]);
      *(f16x4*)&gb[i0 + 16*t + qd*4] = o;
    }
  }
}

// ------ MFMA fp16 GEMM, 8 waves (2m x 4n), BM=256 (2 paired 128-row tiles), BN=256 ----
// EXACT R6/R9 structure (measured fastest: MODE1 61.5 us, 59 MB traffic).
// MODE 0 additionally FUSES the diffusion-embedding add: B is read as f32 from x and
// d[b][c] is added during the register pair-pack (replaces the k_addemb pass).
// A: global_load_lds w16, As[row][8 slots] 128B pitch, slot=(tile*4+kg)^(row&7).
// B: coalesced row loads + register pair-pack into Bs[kp][n], pitch 260 words.
// Grid: 1D + bijective XCD swizzle (consecutive lin share nt -> B-tile L2 locality).
// MODE 0: out fp16 rows mg, mg+256 = W@(x+d) + bias  (in-projection, M=512)
// MODE 1: out fp16 = (gate row mg)*sigmoid(filter row mg+512)  (oW+GLU, M=1024->512)
// MODE 2: out fp32: tile0 -> (x+v)/sqrt2 (residual), tile1 (+256) -> skip  (M=512)
template<int KD, int MODE>
__global__ __launch_bounds__(512) void k_gemm(
    const f16* __restrict__ W, const f16* __restrict__ Bact,
    const float* __restrict__ bias, const float* __restrict__ xres,
    float* __restrict__ outF, f16* __restrict__ outH,
    const float* __restrict__ Bf32, const float* __restrict__ dadd) {
  constexpr int TOFF = (MODE == 1) ? 512 : 256;   // row offset of second A tile
  constexpr int NK = KD/32;
  constexpr int MT = (MODE == 1) ? 4 : 2;         // m-tiles
  __shared__ __align__(16) f16 As[2][128*8*8];    // [buf][row*8+slot][8], 16 KB/buf
  __shared__ __align__(16) uint32_t Bs[2][16*260];// [buf][kp][n], 16.6 KB/buf
  int tid = threadIdx.x;
  int wv = tid >> 6, lane = tid & 63;

  // bijective XCD swizzle (nwg = 128*MT, divisible by 8)
  int nwg = 128*MT;
  int bid = blockIdx.x;
  int lin = (bid & 7)*(nwg >> 3) + (bid >> 3);
  int mt = lin % MT;
  int nt = lin / MT;              // consecutive lin share nt -> B-tile
  int bb = nt >> 3;
  int l0 = (nt & 7)*256;
  int m0 = mt*128;
  int wm = (wv & 1)*64, wn = (wv >> 1)*64;
  int qd = lane >> 4, ln16 = lane & 15;

  f32x4 acc[2][4][4];
  #pragma unroll
  for (int t = 0; t < 2; ++t)
    for (int i = 0; i < 4; ++i)
      for (int j = 0; j < 4; ++j)
        acc[t][i][j] = (f32x4){0.f,0.f,0.f,0.f};

  const f16* Bbase = Bact + (size_t)bb*KD*Lsq + l0;
  const float* Bfb = Bf32 + (size_t)bb*KD*Lsq + l0;
  int q16 = tid >> 5, nch = tid & 31;

  // ---- pipeline helpers ----
  auto stageA = [&](int buf, int kk) {
    #pragma unroll
    for (int i = 0; i < 2; ++i) {
      int gbase = (wv*2 + i)*64;                 // wave-uniform granule base
      int G = gbase + lane;                      // granule id 0..1023
      int row = G >> 3;
      int gsw = (G & 7) ^ (row & 7);             // source granule (tile*4 + kgran)
      int t = gsw >> 2;
      const f16* src = W + (size_t)(m0 + row + t*TOFF)*KD + kk + (gsw & 3)*8;
      gload_lds16(src, &As[buf][gbase*8]);
    }
  };
  f16x8 rb0, rb1;                 // MODE 1/2 staging regs
  float4 r0l, r0h, r1l, r1h;      // MODE 0 staging regs (f32)
  float d0, d1;
  auto loadB = [&](int kk) {
    if constexpr (MODE == 0) {
      const float* b0 = Bfb + (size_t)(kk + 2*q16)*Lsq + nch*8;
      r0l = *(const float4*)b0;      r0h = *(const float4*)(b0 + 4);
      r1l = *(const float4*)(b0 + Lsq); r1h = *(const float4*)(b0 + Lsq + 4);
      d0 = dadd[bb*Cch + kk + 2*q16];
      d1 = dadd[bb*Cch + kk + 2*q16 + 1];
    } else {
      const f16* b0 = Bbase + (size_t)(kk + 2*q16)*Lsq + nch*8;
      rb0 = *(const f16x8*)b0;
      rb1 = *(const f16x8*)(b0 + Lsq);
    }
  };
  auto packB = [&](int buf) {
    union { uint32_t w[8]; u32x4 v[2]; } pk;
    if constexpr (MODE == 0) {
      float a0[8] = {r0l.x,r0l.y,r0l.z,r0l.w,r0h.x,r0h.y,r0h.z,r0h.w};
      float a1[8] = {r1l.x,r1l.y,r1l.z,r1l.w,r1h.x,r1h.y,r1h.z,r1h.w};
      #pragma unroll
      for (int e = 0; e < 8; ++e) {
        union { f16 h2[2]; uint32_t u; } t2;
        t2.h2[0] = (f16)(a0[e] + d0); t2.h2[1] = (f16)(a1[e] + d1);
        pk.w[e] = t2.u;
      }
    } else {
      #pragma unroll
      for (int e = 0; e < 8; ++e) {
        union { f16 h2[2]; uint32_t u; } t2;
        t2.h2[0] = rb0[e]; t2.h2[1] = rb1[e];
        pk.w[e] = t2.u;
      }
    }
    *(u32x4*)&Bs[buf][q16*260 + nch*8]     = pk.v[0];
    *(u32x4*)&Bs[buf][q16*260 + nch*8 + 4] = pk.v[1];
  };
  auto compute = [&](int buf) {
    f16x8 afr[2][4];
    #pragma unroll
    for (int i = 0; i < 4; ++i)
      for (int t = 0; t < 2; ++t) {
        int row = wm + i*16 + ln16;
        int g = (t*4 + qd) ^ (row & 7);          // undo source swizzle
        afr[t][i] = *(const f16x8*)&As[buf][(row*8 + g)*8];
      }
    f16x8 bfr[4];
    #pragma unroll
    for (int j = 0; j < 4; ++j) {
      union { uint32_t w2[4]; f16x8 v; } bu;
      #pragma unroll
      for (int r2 = 0; r2 < 4; ++r2) bu.w2[r2] = Bs[buf][(qd*4 + r2)*260 + wn + j*16 + ln16];
      bfr[j] = bu.v;
    }
    __builtin_amdgcn_s_setprio(1);
    #pragma unroll
    for (int j = 0; j < 4; ++j)
      for (int i = 0; i < 4; ++i)
        for (int t = 0; t < 2; ++t)
          acc[t][i][j] = __builtin_amdgcn_mfma_f32_16x16x32_f16(afr[t][i], bfr[j], acc[t][i][j], 0, 0, 0);
    __builtin_amdgcn_s_setprio(0);
  };

  // ---- prologue: fill buffer 0 ----
  stageA(0, 0);
  loadB(0);
  packB(0);
  __syncthreads();

  int cur = 0;
  for (int t = 0; t < NK; ++t) {
    if (t + 1 < NK) {                            // issue next-tile loads EARLY
      stageA(cur ^ 1, (t + 1)*32);
      loadB((t + 1)*32);
    }
    compute(cur);                                // hides the load latency
    if (t + 1 < NK) packB(cur ^ 1);              // write-late (rb done by now)
    __syncthreads();                             // single drain+publish per K-step
    cur ^= 1;
  }

  #pragma unroll
  for (int i = 0; i < 4; ++i)
    for (int j = 0; j < 4; ++j)
      for (int r = 0; r < 4; ++r) {
        int ml = wm + i*16 + qd*4 + r;
        int nl = wn + j*16 + ln16;
        int mg = m0 + ml;
        int l  = l0 + nl;
        if (MODE == 0) {
          outH[((size_t)bb*Hch + mg)*Lsq + l]       = (f16)(acc[0][i][j][r] + bias[mg]);
          outH[((size_t)bb*Hch + mg + 256)*Lsq + l] = (f16)(acc[1][i][j][r] + bias[mg + 256]);
        } else if (MODE == 1) {
          float va = acc[0][i][j][r] + bias[mg];
          float vb = acc[1][i][j][r] + bias[512 + mg];
          outH[((size_t)bb*Hch + mg)*Lsq + l] = (f16)(va * sigmoidf_(vb));
        } else {
          size_t idx = ((size_t)bb*Cch + mg)*Lsq + l;
          float v0 = acc[0][i][j][r] + bias[mg];
          outF[idx] = (v0 + xres[idx]) * 0.7071067811865476f;
          float v1 = acc[1][i][j][r] + bias[mg + 256];
          outF[(size_t)Bsz*Cch*Lsq + idx] = v1;
        }
      }
}

// ---------------- LayerNorm over channels (fp16 in) — R12-proven version ----------------
template<int MODE>
__global__ __launch_bounds__(256) void k_ln(const f16* __restrict__ v,
                                            const float* __restrict__ gam, const float* __restrict__ bet,
                                            float* __restrict__ outF, f16* __restrict__ outH) {
  __shared__ float red[2][4][64];
  int b = blockIdx.x >> 5;
  int l = (blockIdx.x & 31)*64 + (threadIdx.x & 63);
  int wv = threadIdx.x >> 6, lane = threadIdx.x & 63;
  const f16* base = v + (size_t)b*Hch*Lsq + l;
  float s = 0.f, s2 = 0.f;
  for (int h = wv*128; h < wv*128 + 128; ++h) {
    float xv = (float)base[(size_t)h*Lsq];
    s += xv; s2 += xv*xv;
  }
  red[0][wv][lane] = s; red[1][wv][lane] = s2;
  __syncthreads();
  s  = red[0][0][lane] + red[0][1][lane] + red[0][2][lane] + red[0][3][lane];
  s2 = red[1][0][lane] + red[1][1][lane] + red[1][2][lane] + red[1][3][lane];
  float mu = s*(1.0f/Hch);
  float var = s2*(1.0f/Hch) - mu*mu;
  float rs = rsqrtf(var + 1e-5f);
  if (MODE == 0) {
    f16* ob = outH + (size_t)b*Hch*Lsq + l;
    for (int h = wv*128; h < wv*128 + 128; ++h)
      ob[(size_t)h*Lsq] = (f16)(((float)base[(size_t)h*Lsq] - mu)*rs*gam[h] + bet[h]);
  } else {
    f16* ob = outH + (size_t)b*Cch*Lsq + l;
    for (int c = wv*64; c < wv*64 + 64; ++c) {
      float xg = ((float)base[(size_t)c*Lsq] - mu)*rs*gam[c] + bet[c];
      float xf = ((float)base[(size_t)(c+Cch)*Lsq] - mu)*rs*gam[c+Cch] + bet[c+Cch];
      float xfc = fminf(fmaxf(xf, -15.f), 15.f);
      float e = __expf(2.f*xfc);
      ob[(size_t)c*Lsq] = (f16)(sigmoidf_(xg) * ((e-1.f)/(e+1.f)));
    }
  }
}

// ---------------- launch ----------------
extern "C" void kernel_launch(void* const* d_in, const int* in_sizes, int n_in,
                              void* d_out, int out_size, void* d_ws, size_t ws_size,
                              hipStream_t stream) {
  const float* x    = (const float*)d_in[0];
  const float* emb  = (const float*)d_in[1];
  const float* dpW  = (const float*)d_in[2];
  const float* dpb  = (const float*)d_in[3];
  const float* inW  = (const float*)d_in[4];
  const float* inb  = (const float*)d_in[5];
  const float* outW = (const float*)d_in[6];
  const float* outb = (const float*)d_in[7];
  const float* ln1g = (const float*)d_in[8];
  const float* ln1b = (const float*)d_in[9];
  const float* ln2g = (const float*)d_in[10];
  const float* ln2b = (const float*)d_in[11];
  const float* s4[2][8];
  for (int ly = 0; ly < 2; ++ly)
    for (int k = 0; k < 8; ++k) s4[ly][k] = (const float*)d_in[12 + ly*8 + k];
  // s4[ly]: 0 log_dt, 1 A_re, 2 A_im, 3 C_re, 4 C_im, 5 D, 6 oW, 7 ob

  char* p = (char*)d_ws;
  auto alloc = [&](size_t bytes) { char* r = p; p += (bytes + 255) & ~(size_t)255; return r; };
  f16* inW16  = (f16*)alloc((size_t)Hch*Cch*2);
  f16* oW16_0 = (f16*)alloc((size_t)2*Hch*Hch*2);
  f16* oW16_1 = (f16*)alloc((size_t)2*Hch*Hch*2);
  f16* outW16 = (f16*)alloc((size_t)2*Cch*Cch*2);
  float* dbuf = (float*)alloc((size_t)Bsz*Cch*4);
  f16* kge[2], *kgo[2];
  for (int ly = 0; ly < 2; ++ly) {
    kge[ly] = (f16*)alloc((size_t)Hch*KGP*2);
    kgo[ly] = (f16*)alloc((size_t)Hch*KGP*2);
  }
  f16*  xd   = (f16*)alloc((size_t)Bsz*Cch*Lsq*2);
  f16*  u16g = (f16*)alloc((size_t)Bsz*Hch*Lsq*2);
  f16*  gbuf = (f16*)alloc((size_t)Bsz*Hch*Lsq*2);
  f16*  glu  = (f16*)alloc((size_t)Bsz*Hch*Lsq*2);
  f16*  oW16[2] = {oW16_0, oW16_1};

  // prep: ONE launch (emb matvec | weight f2h | kgen both layers)
  k_prep<<<3328, 256, 0, stream>>>(
      emb, dpW, dpb, dbuf,
      inW, inW16, s4[0][6], oW16_0, s4[1][6], oW16_1, outW, outW16,
      s4[0][0], s4[0][1], s4[0][2], s4[0][3], s4[0][4], s4[0][5],
      s4[1][0], s4[1][1], s4[1][2], s4[1][3], s4[1][4], s4[1][5],
      kge[0], kgo[0], kge[1], kgo[1]);

  dim3 bl(512);
  // in-projection (fp16 out), diffusion-emb add fused into B staging
  k_gemm<Cch, 0><<<256, bl, 0, stream>>>(inW16, nullptr, inb, nullptr, nullptr, u16g, x, dbuf);
  // S4 layer 1
  k_conv<<<Hch, 512, 0, stream>>>(u16g, kge[0], kgo[0], gbuf);
  k_gemm<Hch, 1><<<512, bl, 0, stream>>>(oW16[0], gbuf, s4[0][7], nullptr, nullptr, glu, nullptr, nullptr);
  k_ln<0><<<Bsz*32, 256, 0, stream>>>(glu, ln1g, ln1b, nullptr, u16g);
  // S4 layer 2
  k_conv<<<Hch, 512, 0, stream>>>(u16g, kge[1], kgo[1], gbuf);
  k_gemm<Hch, 1><<<512, bl, 0, stream>>>(oW16[1], gbuf, s4[1][7], nullptr, nullptr, glu, nullptr, nullptr);
  k_ln<1><<<Bsz*32, 256, 0, stream>>>(glu, ln2g, ln2b, nullptr, xd);
  // out-projection (+ residual/skip split)
  k_gemm<Cch, 2><<<256, bl, 0, stream>>>(outW16, xd, outb, x, (float*)d_out, nullptr, nullptr, nullptr);
}